// Round 16
// baseline (211.610 us; speedup 1.0000x reference)
//
#include <hip/hip_runtime.h>
#include <math.h>

// Problem constants
#define NTOK 4096
#define PCH  128
#define ICH  256
#define OCH  128
#define NB   2
#define SCALEF 0.08838834764831845f   // 1/sqrt(128)

typedef __bf16 bf16_t;
typedef __attribute__((ext_vector_type(8))) __bf16 bf16x8;
typedef __attribute__((ext_vector_type(4))) __bf16 bf16x4;
typedef __attribute__((ext_vector_type(4))) float floatx4;

#define LDK 136   // padded row length (bf16) for k=128 tiles
#define LDJ 72    // padded row length (bf16) for j=64 Es tiles

// ---------------------------------------------------------------------------
// K0: merged pack — y<2: pf -> pfC + pfT;  y>=2: img -> imgT (token-major)
// ---------------------------------------------------------------------------
__global__ __launch_bounds__(256) void pack_all(const float* __restrict__ pf,
                                                const float* __restrict__ img,
                                                bf16_t* __restrict__ pfC,
                                                bf16_t* __restrict__ pfT,
                                                bf16_t* __restrict__ imgT)
{
    __shared__ float Ls[64][65];
    const int t = threadIdx.x;
    const int n0 = blockIdx.x * 64, b = blockIdx.z;
    const bool ispf = blockIdx.y < 2;
    const int d0 = ispf ? blockIdx.y * 64 : (blockIdx.y - 2) * 64;
    const float* src = (ispf ? pf + ((size_t)(b * PCH + d0)) * NTOK
                             : img + ((size_t)(b * ICH + d0)) * NTOK) + n0;
#pragma unroll
    for (int p = 0; p < 4; p++) {
        int d = p * 16 + (t >> 4), c = t & 15;
        float4 v = *(const float4*)&src[d * NTOK + c * 4];
        Ls[d][c * 4 + 0] = v.x; Ls[d][c * 4 + 1] = v.y;
        Ls[d][c * 4 + 2] = v.z; Ls[d][c * 4 + 3] = v.w;
        if (ispf) {
            bf16x4 o = { (bf16_t)v.x, (bf16_t)v.y, (bf16_t)v.z, (bf16_t)v.w };
            *(bf16x4*)&pfC[((size_t)(b * PCH + d0 + d)) * NTOK + n0 + c * 4] = o;
        }
    }
    __syncthreads();
#pragma unroll
    for (int p = 0; p < 2; p++) {
        int n = p * 32 + (t >> 3), c = t & 7;
        bf16x8 o;
#pragma unroll
        for (int k = 0; k < 8; k++) o[k] = (bf16_t)Ls[c * 8 + k][n];
        if (ispf)
            *(bf16x8*)&pfT[((size_t)(b * NTOK + n0 + n)) * PCH + d0 + c * 8] = o;
        else
            *(bf16x8*)&imgT[((size_t)(b * NTOK + n0 + n)) * ICH + d0 + c * 8] = o;
    }
}

// ---------------------------------------------------------------------------
// K1: fc2 (MFMA) — ri[p][n] = sum_c w[p][c]*img[c][n] + bias[p]
// Also zeroes the zsum buffers (16384 floats) in its prologue.
// ---------------------------------------------------------------------------
__global__ __launch_bounds__(256) void fc2_mfma(const bf16_t* __restrict__ imgT,
                                                const float* __restrict__ w,
                                                const float* __restrict__ bias,
                                                bf16_t* __restrict__ riC,
                                                bf16_t* __restrict__ riT,
                                                float* __restrict__ zsums)
{
    const int t = threadIdx.x;
    if (blockIdx.y == 0 && blockIdx.z == 0)
        zsums[blockIdx.x * 256 + t] = 0.f;       // 64 blocks x 256 = 16384 floats

    const int n0 = blockIdx.x * 64, pbase = blockIdx.y * 64, b = blockIdx.z;
    const int lane = t & 63, wv = t >> 6, tx = lane & 15, q = lane >> 4;
    const int n = n0 + wv * 16 + tx;
    const bf16_t* trow = imgT + ((size_t)(b * NTOK + n)) * ICH;

    floatx4 acc[4];
#pragma unroll
    for (int ot = 0; ot < 4; ot++) acc[ot] = (floatx4){0.f, 0.f, 0.f, 0.f};

#pragma unroll
    for (int s = 0; s < 8; s++) {
        bf16x8 bf = *(const bf16x8*)&trow[s * 32 + q * 8];
#pragma unroll
        for (int ot = 0; ot < 4; ot++) {
            const float* wr = w + (size_t)(pbase + ot * 16 + tx) * ICH + s * 32 + q * 8;
            float4 x0 = *(const float4*)wr;
            float4 x1 = *(const float4*)(wr + 4);
            bf16x8 af;
            af[0] = (bf16_t)x0.x; af[1] = (bf16_t)x0.y; af[2] = (bf16_t)x0.z; af[3] = (bf16_t)x0.w;
            af[4] = (bf16_t)x1.x; af[5] = (bf16_t)x1.y; af[6] = (bf16_t)x1.z; af[7] = (bf16_t)x1.w;
            acc[ot] = __builtin_amdgcn_mfma_f32_16x16x32_bf16(af, bf, acc[ot], 0, 0, 0);
        }
    }

#pragma unroll
    for (int ot = 0; ot < 4; ot++) {
        bf16x4 tv;
#pragma unroll
        for (int r = 0; r < 4; r++) {
            const int p = pbase + ot * 16 + q * 4 + r;
            float v = acc[ot][r] + bias[p];
            tv[r] = (bf16_t)v;
            riC[((size_t)(b * PCH + p)) * NTOK + n] = (bf16_t)v;
        }
        *(bf16x4*)&riT[((size_t)(b * NTOK + n)) * PCH + pbase + ot * 16 + q * 4] = tv;
    }
}

// ---------------------------------------------------------------------------
// K2: stats v5 + XCD swizzle + fus-zero prologue (kept from R15 — stats is
// off the top-5 and folding the 8MB zero here is a structural win).
// ---------------------------------------------------------------------------
__global__ __launch_bounds__(256, 4) void stats_mfma(const bf16_t* __restrict__ pfT,
                                                     const bf16_t* __restrict__ riT,
                                                     float* __restrict__ zr,
                                                     float* __restrict__ zc,
                                                     float* __restrict__ fus)
{
    __shared__ bf16_t As[64 * LDK];
    __shared__ float zacc[1024];
    const int t = threadIdx.x;
    const int blk = blockIdx.x;

    { // zero fus: 512 blocks x 256 thr x 4 float4 = 2,097,152 floats exactly
        float4* f4 = (float4*)fus + ((size_t)blk * 256 + t) * 4;
        f4[0] = float4{0.f, 0.f, 0.f, 0.f};
        f4[1] = float4{0.f, 0.f, 0.f, 0.f};
        f4[2] = float4{0.f, 0.f, 0.f, 0.f};
        f4[3] = float4{0.f, 0.f, 0.f, 0.f};
    }

    const int g = blk & 7, slot = blk >> 3;      // XCD-aware decode
    const int b = g & 1, js = g >> 1;
    const bf16_t* At = pfT + (size_t)b * NTOK * PCH;
    const bf16_t* Bt = riT + (size_t)b * NTOK * PCH;
    float* zrow = zr + (size_t)b * NTOK;
    float* zcol = zc + (size_t)b * NTOK;
    const int lane = t & 63, w = t >> 6, tx = lane & 15, q = lane >> 4;
    const int i0 = slot * 64;
    const int jbase = js * 1024;
    const int sr = t >> 4, sc = t & 15;
    const bf16_t* Brow = Bt + (size_t)(jbase + w * 16 + tx) * PCH;

    bf16x8 bcur[4];
#pragma unroll
    for (int s = 0; s < 4; s++)
        bcur[s] = *(const bf16x8*)&Brow[s * 32 + q * 8];
#pragma unroll
    for (int p = 0; p < 4; p++) {
        int i = p * 16 + sr;
        *(uint4*)&As[i * LDK + sc * 8] = *(const uint4*)&At[((size_t)(i0 + i)) * PCH + sc * 8];
    }
    __syncthreads();
    bf16x8 af[4][4];
#pragma unroll
    for (int mt = 0; mt < 4; mt++)
#pragma unroll
        for (int s = 0; s < 4; s++)
            af[mt][s] = *(bf16x8*)&As[(mt * 16 + tx) * LDK + s * 32 + q * 8];

    float racc[4] = {0.f, 0.f, 0.f, 0.f};
    for (int jt = 0; jt < 16; jt++) {
        __builtin_amdgcn_s_barrier();            // pacing only
        floatx4 sacc[4];
#pragma unroll
        for (int mt = 0; mt < 4; mt++) {
            sacc[mt] = (floatx4){0.f, 0.f, 0.f, 0.f};
#pragma unroll
            for (int s = 0; s < 4; s++)
                sacc[mt] = __builtin_amdgcn_mfma_f32_16x16x32_bf16(bcur[s], af[mt][s], sacc[mt], 0, 0, 0);
        }
        if (jt < 15) {
            const bf16_t* bn = Brow + (size_t)(jt + 1) * 64 * PCH;
#pragma unroll
            for (int s = 0; s < 4; s++)
                bcur[s] = *(const bf16x8*)&bn[s * 32 + q * 8];
        }

        float ctmp[4] = {0.f, 0.f, 0.f, 0.f};
#pragma unroll
        for (int mt = 0; mt < 4; mt++)
#pragma unroll
            for (int r = 0; r < 4; r++) {
                float e = __expf(sacc[mt][r] * SCALEF);
                racc[mt] += e;
                ctmp[r]  += e;
            }
#pragma unroll
        for (int r = 0; r < 4; r++) {
            float v = ctmp[r];
            v += __shfl_xor(v, 1); v += __shfl_xor(v, 2);
            v += __shfl_xor(v, 4); v += __shfl_xor(v, 8);
            if (tx == 0) zacc[jt * 64 + w * 16 + q * 4 + r] = v;
        }
    }
#pragma unroll
    for (int mt = 0; mt < 4; mt++) {
        float v = racc[mt];
        v += __shfl_xor(v, 16);
        v += __shfl_xor(v, 32);
        if (q == 0) atomicAdd(&zrow[i0 + mt * 16 + tx], v);
    }
    __syncthreads();
#pragma unroll
    for (int k = 0; k < 4; k++)
        atomicAdd(&zcol[jbase + k * 256 + t], zacc[k * 256 + t]);
}

// ---------------------------------------------------------------------------
// K3: attn — REVERTED to R13's proven 2D-grid dispatch (no XCD swizzle).
// R15's swizzle cut FETCH 34->12MB but COST 9us: never HBM-bound, and
// lockstepped js-groups made the 4-way fus atomic collisions temporally
// coincident cross-XCD. Natural round-robin staggers them.
// ---------------------------------------------------------------------------
__global__ __launch_bounds__(256, 3) void attn_mfma(const bf16_t* __restrict__ pfT,
                                                    const bf16_t* __restrict__ riT,
                                                    const bf16_t* __restrict__ pfC,
                                                    const bf16_t* __restrict__ riC,
                                                    const float* __restrict__ zrsum,
                                                    const float* __restrict__ zcsum,
                                                    float* __restrict__ fus)
{
    __shared__ bf16_t As[64 * LDK];
    __shared__ bf16_t Es[2][64 * LDJ];
    const int b = blockIdx.y, t = threadIdx.x;
    const int mode = blockIdx.z >> 2, js = blockIdx.z & 3;
    const bf16_t* At = (mode == 0 ? pfT : riT) + (size_t)b * NTOK * PCH;
    const bf16_t* Bt = (mode == 0 ? riT : pfT) + (size_t)b * NTOK * PCH;
    const bf16_t* Vc = (mode == 0 ? pfC : riC) + (size_t)b * PCH * NTOK;
    const float* wsum = (mode == 0 ? zcsum : zrsum) + (size_t)b * NTOK;
    const int lane = t & 63, w = t >> 6, tx = lane & 15, q = lane >> 4;
    const int i0 = blockIdx.x * 64;
    const int jbase = js * 1024;
    const int sr = t >> 4, sc = t & 15;
    const bf16_t* Brow = Bt + (size_t)(jbase + w * 16 + tx) * PCH;

    bf16x8 bcur[4];
#pragma unroll
    for (int s = 0; s < 4; s++)
        bcur[s] = *(const bf16x8*)&Brow[s * 32 + q * 8];
    bf16x8 vcur[2][2];
#pragma unroll
    for (int nt = 0; nt < 2; nt++)
#pragma unroll
        for (int s = 0; s < 2; s++)
            vcur[nt][s] = *(const bf16x8*)&Vc[((size_t)(w * 32 + nt * 16 + tx)) * NTOK + jbase + s * 32 + q * 8];
    float4 wv = *(const float4*)&wsum[jbase + w * 16 + q * 4];
    float4 wr4 = {1.f / wv.x, 1.f / wv.y, 1.f / wv.z, 1.f / wv.w};

#pragma unroll
    for (int p = 0; p < 4; p++) {
        int i = p * 16 + sr;
        *(uint4*)&As[i * LDK + sc * 8] = *(const uint4*)&At[((size_t)(i0 + i)) * PCH + sc * 8];
    }
    __syncthreads();
    bf16x8 af[4][4];
#pragma unroll
    for (int mt = 0; mt < 4; mt++)
#pragma unroll
        for (int s = 0; s < 4; s++)
            af[mt][s] = *(bf16x8*)&As[(mt * 16 + tx) * LDK + s * 32 + q * 8];

    floatx4 outacc[4][2];
#pragma unroll
    for (int mt = 0; mt < 4; mt++)
#pragma unroll
        for (int nt = 0; nt < 2; nt++)
            outacc[mt][nt] = (floatx4){0.f, 0.f, 0.f, 0.f};

    for (int jt = 0; jt < 16; jt++) {
        const int cur = jt & 1;
        const int j0 = jbase + jt * 64;

        floatx4 sacc[4];
#pragma unroll
        for (int mt = 0; mt < 4; mt++) {
            sacc[mt] = (floatx4){0.f, 0.f, 0.f, 0.f};
#pragma unroll
            for (int s = 0; s < 4; s++)
                sacc[mt] = __builtin_amdgcn_mfma_f32_16x16x32_bf16(bcur[s], af[mt][s], sacc[mt], 0, 0, 0);
        }
        if (jt < 15) {
            const bf16_t* bn = Brow + (size_t)(jt + 1) * 64 * PCH;
#pragma unroll
            for (int s = 0; s < 4; s++)
                bcur[s] = *(const bf16x8*)&bn[s * 32 + q * 8];
        }

#pragma unroll
        for (int mt = 0; mt < 4; mt++) {
            bf16x4 ev;
#pragma unroll
            for (int r = 0; r < 4; r++)
                ev[r] = (bf16_t)(__expf(sacc[mt][r] * SCALEF) * ((const float*)&wr4)[r]);
            *(bf16x4*)&Es[cur][(mt * 16 + tx) * LDJ + w * 16 + q * 4] = ev;
        }
        float4 wnv;
        if (jt < 15)
            wnv = *(const float4*)&wsum[j0 + 64 + w * 16 + q * 4];

        __syncthreads();

        bf16x8 ef[4][2];
#pragma unroll
        for (int mt = 0; mt < 4; mt++)
#pragma unroll
            for (int s = 0; s < 2; s++)
                ef[mt][s] = *(bf16x8*)&Es[cur][(mt * 16 + tx) * LDJ + s * 32 + q * 8];
#pragma unroll
        for (int nt = 0; nt < 2; nt++)
#pragma unroll
            for (int s = 0; s < 2; s++)
#pragma unroll
                for (int mt = 0; mt < 4; mt++)
                    outacc[mt][nt] = __builtin_amdgcn_mfma_f32_16x16x32_bf16(ef[mt][s], vcur[nt][s], outacc[mt][nt], 0, 0, 0);

        if (jt < 15) {
#pragma unroll
            for (int nt = 0; nt < 2; nt++)
#pragma unroll
                for (int s = 0; s < 2; s++)
                    vcur[nt][s] = *(const bf16x8*)&Vc[((size_t)(w * 32 + nt * 16 + tx)) * NTOK + (j0 + 64) + s * 32 + q * 8];
            wr4 = (float4){1.f / wnv.x, 1.f / wnv.y, 1.f / wnv.z, 1.f / wnv.w};
        }
    }

    float* fo = fus + ((size_t)(b * NTOK + i0)) * 256 + mode * 128 + w * 32;
#pragma unroll
    for (int mt = 0; mt < 4; mt++)
#pragma unroll
        for (int nt = 0; nt < 2; nt++)
#pragma unroll
            for (int r = 0; r < 4; r++)
                atomicAdd(&fo[(mt * 16 + q * 4 + r) * 256 + nt * 16 + tx], outacc[mt][nt][r]);
}

// ---------------------------------------------------------------------------
// K4: conv (MFMA) — out[o][n] = relu(bn(sum_c cw[o][c]*fus[n][c] + cb))
// ---------------------------------------------------------------------------
__global__ __launch_bounds__(256) void conv_mfma(const float* __restrict__ fus,
                                                 const float* __restrict__ cw,
                                                 const float* __restrict__ cb,
                                                 const float* __restrict__ g,
                                                 const float* __restrict__ be,
                                                 const float* __restrict__ mu,
                                                 const float* __restrict__ var,
                                                 float* __restrict__ out)
{
    const int t = threadIdx.x;
    const int n0 = blockIdx.x * 64, obase = blockIdx.y * 64, b = blockIdx.z;
    const int lane = t & 63, wv = t >> 6, tx = lane & 15, q = lane >> 4;
    const int n = n0 + wv * 16 + tx;
    const float* frow = fus + ((size_t)(b * NTOK + n)) * 256;

    floatx4 acc[4];
#pragma unroll
    for (int ot = 0; ot < 4; ot++) acc[ot] = (floatx4){0.f, 0.f, 0.f, 0.f};

#pragma unroll
    for (int s = 0; s < 8; s++) {
        float4 f0 = *(const float4*)&frow[s * 32 + q * 8];
        float4 f1 = *(const float4*)&frow[s * 32 + q * 8 + 4];
        bf16x8 bf;
        bf[0] = (bf16_t)f0.x; bf[1] = (bf16_t)f0.y; bf[2] = (bf16_t)f0.z; bf[3] = (bf16_t)f0.w;
        bf[4] = (bf16_t)f1.x; bf[5] = (bf16_t)f1.y; bf[6] = (bf16_t)f1.z; bf[7] = (bf16_t)f1.w;
#pragma unroll
        for (int ot = 0; ot < 4; ot++) {
            const float* wr = cw + (size_t)(obase + ot * 16 + tx) * 256 + s * 32 + q * 8;
            float4 x0 = *(const float4*)wr;
            float4 x1 = *(const float4*)(wr + 4);
            bf16x8 af;
            af[0] = (bf16_t)x0.x; af[1] = (bf16_t)x0.y; af[2] = (bf16_t)x0.z; af[3] = (bf16_t)x0.w;
            af[4] = (bf16_t)x1.x; af[5] = (bf16_t)x1.y; af[6] = (bf16_t)x1.z; af[7] = (bf16_t)x1.w;
            acc[ot] = __builtin_amdgcn_mfma_f32_16x16x32_bf16(af, bf, acc[ot], 0, 0, 0);
        }
    }

#pragma unroll
    for (int ot = 0; ot < 4; ot++)
#pragma unroll
        for (int r = 0; r < 4; r++) {
            const int o = obase + ot * 16 + q * 4 + r;
            const float sc = g[o] * rsqrtf(var[o] + 1e-5f);
            const float b0 = be[o] + (cb[o] - mu[o]) * sc;
            float y = acc[ot][r] * sc + b0;
            out[((size_t)(b * OCH + o)) * NTOK + n] = fmaxf(y, 0.f);
        }
}

// ---------------------------------------------------------------------------
extern "C" void kernel_launch(void* const* d_in, const int* in_sizes, int n_in,
                              void* d_out, int out_size, void* d_ws, size_t ws_size,
                              hipStream_t stream)
{
    const float* pf   = (const float*)d_in[0];
    const float* img  = (const float*)d_in[1];
    const float* fc2w = (const float*)d_in[2];
    const float* fc2b = (const float*)d_in[3];
    const float* cw   = (const float*)d_in[4];
    const float* cb   = (const float*)d_in[5];
    const float* g    = (const float*)d_in[6];
    const float* be   = (const float*)d_in[7];
    const float* mu   = (const float*)d_in[8];
    const float* var  = (const float*)d_in[9];
    float* out = (float*)d_out;

    // ws layout: proven footprint (16,842,752 B). imgT aliases fus region
    // (dead after fc2; fus is zeroed inside stats which runs after fc2).
    float* fus   = (float*)d_ws;                              // 8 MB
    float* zrsum = fus + (size_t)NB * NTOK * 256;             // 32 KB
    float* zcsum = zrsum + NB * NTOK;                         // 32 KB (contiguous after zrsum)
    bf16_t* pfC = (bf16_t*)(zcsum + NB * NTOK);               // 2 MB
    bf16_t* pfT = pfC + (size_t)NB * PCH * NTOK;              // 2 MB
    bf16_t* riC = pfT + (size_t)NB * NTOK * PCH;              // 2 MB
    bf16_t* riT = riC + (size_t)NB * PCH * NTOK;              // 2 MB
    bf16_t* imgT = (bf16_t*)fus;                              // 4 MB alias

    pack_all  <<<dim3(64, 6, NB), 256, 0, stream>>>(pf, img, pfC, pfT, imgT);
    fc2_mfma  <<<dim3(64, 2, NB), 256, 0, stream>>>(imgT, fc2w, fc2b, riC, riT, zrsum);
    stats_mfma<<<dim3(512),       256, 0, stream>>>(pfT, riT, zrsum, zcsum, fus);
    attn_mfma <<<dim3(64, NB, 8), 256, 0, stream>>>(pfT, riT, pfC, riC, zrsum, zcsum, fus);
    conv_mfma <<<dim3(64, 2, NB), 256, 0, stream>>>(fus, cw, cb, g, be, mu, var, out);
}